// Round 5
// baseline (522.044 us; speedup 1.0000x reference)
//
#include <hip/hip_runtime.h>
#include <math.h>

#define BB 512
#define TT 1024
#define KK 48
#define PF 4      // emission prefetch depth (steps) for the MFMA denominator

typedef __attribute__((ext_vector_type(4))) short short4v;
typedef __attribute__((ext_vector_type(4))) float floatx4;

static constexpr float L2E = 1.4426950408889634f;   // log2(e)
static constexpr float LN2 = 0.6931471805599453f;   // ln(2)

__device__ __forceinline__ float wave_reduce_sum_f(float v) {
    #pragma unroll
    for (int m = 32; m >= 1; m >>= 1) v += __shfl_xor(v, m, 64);
    return v;
}
__device__ __forceinline__ int wave_reduce_sum_i(int v) {
    #pragma unroll
    for (int m = 32; m >= 1; m >>= 1) v += __shfl_xor(v, m, 64);
    return v;
}

__device__ __forceinline__ floatx4 mfma16(short4v a, short4v b, floatx4 c) {
#if __has_builtin(__builtin_amdgcn_mfma_f32_16x16x16bf16_1k)
    return __builtin_amdgcn_mfma_f32_16x16x16bf16_1k(a, b, c, 0, 0, 0);
#else
    floatx4 d;
    asm volatile("v_mfma_f32_16x16x16_bf16 %0, %1, %2, %3"
                 : "=v"(d) : "v"(a), "v"(b), "v"(c));
    return d;
#endif
}

// round-half-up f32->bf16, pack two into one dword (x -> low16, y -> high16)
__device__ __forceinline__ unsigned pk_bf16(float x, float y) {
    unsigned ux = __float_as_uint(x) + 0x8000u;
    unsigned uy = __float_as_uint(y) + 0x8000u;
    return (ux >> 16) | (uy & 0xffff0000u);
}
__device__ __forceinline__ short4v mk4(unsigned lo, unsigned hi) {
    union { unsigned u[2]; short4v s; } cv;
    cv.u[0] = lo; cv.u[1] = hi; return cv.s;
}
__device__ __forceinline__ unsigned gu(short4v v, int half) {
    union { short4v s; unsigned u[2]; } cv; cv.s = v; return cv.u[half];
}

// Fused kernel: blocks [0,512) = numerator (one wave per batch, round-4 code),
// blocks [512,544) = MFMA denominator (one wave per 16 batches).
__global__ __launch_bounds__(64) void crf_fused(
    const float* __restrict__ emissions,   // (B, T, K)
    const int*   __restrict__ tags,        // (B, T)
    const void*  __restrict__ mask,        // (B, T) — dtype probed
    const float* __restrict__ transitions, // (K, K)
    const float* __restrict__ start_t,     // (K,)
    const float* __restrict__ end_t,       // (K,)
    float*       __restrict__ ws_s,        // (B,) path scores
    float*       __restrict__ ws_d)        // (B,) log-denominators
{
    const int lane = threadIdx.x;
    const unsigned w0 = *((const unsigned*)mask);
    __shared__ int sL[16];

    if (blockIdx.x < BB) {
        // ================= numerator (verbatim round-4 logic) =================
        const int b = blockIdx.x;
        const float* em = emissions + (size_t)b * TT * KK;
        const int*   tg = tags      + (size_t)b * TT;
        int c = 0;
        if (w0 == 1u) {
            const int* mp = (const int*)mask + (size_t)b * TT;
            for (int t = lane; t < TT; t += 64) c += (mp[t] != 0);
        } else if (w0 == 0x3f800000u) {
            const float* mp = (const float*)mask + (size_t)b * TT;
            for (int t = lane; t < TT; t += 64) c += (mp[t] != 0.0f);
        } else {
            const unsigned char* mp = (const unsigned char*)mask + (size_t)b * TT;
            for (int t = lane; t < TT; t += 64) c += (mp[t] != 0);
        }
        const int L = wave_reduce_sum_i(c);
        float sc = 0.0f;
        for (int t = lane; t < TT; t += 64) {
            if (t < L) {
                const int tagt = tg[t];
                float term = em[(size_t)t * KK + tagt];
                term += (t == 0) ? start_t[tagt] : transitions[tg[t - 1] * KK + tagt];
                sc += term;
            }
        }
        sc = wave_reduce_sum_f(sc);
        if (lane == 0) ws_s[b] = sc + end_t[tg[L - 1]];
        return;
    }

    // ================= denominator: 16 batches per wave via MFMA =================
    const int grp  = blockIdx.x - BB;
    const int base = grp * 16;
    const int n = lane & 15;        // column  = batch within group
    const int g = lane >> 4;        // quad group: rows 4g..4g+3 per tile
    const int bn = base + n;
    const float* emn = emissions + (size_t)bn * TT * KK;

    // ---- per-batch lengths ----
    for (int nb = 0; nb < 16; ++nb) {
        int c = 0; const size_t b2 = base + nb;
        if (w0 == 1u) {
            const int* mp = (const int*)mask + b2 * TT;
            for (int t = lane; t < TT; t += 64) c += (mp[t] != 0);
        } else if (w0 == 0x3f800000u) {
            const float* mp = (const float*)mask + b2 * TT;
            for (int t = lane; t < TT; t += 64) c += (mp[t] != 0.0f);
        } else {
            const unsigned char* mp = (const unsigned char*)mask + b2 * TT;
            for (int t = lane; t < TT; t += 64) c += (mp[t] != 0);
        }
        c = wave_reduce_sum_i(c);
        if (lane == 0) sL[nb] = c;
    }
    __syncthreads();
    const int Lc = sL[n];           // this lane's column length
    int Lmax = Lc;
    #pragma unroll
    for (int m = 32; m >= 1; m >>= 1) Lmax = max(Lmax, __shfl_xor(Lmax, m, 64));

    // ---- A fragments: M[j][i] = exp(transitions[j][i]), bf16, constant ----
    // A_{mt,kt}: lane holds A[16mt + n][16kt + 4g + c], c = 0..3
    short4v A[3][3];
    #pragma unroll
    for (int mt = 0; mt < 3; ++mt) {
        const int j = 16 * mt + n;
        #pragma unroll
        for (int kt = 0; kt < 3; ++kt) {
            const int i0 = 16 * kt + 4 * g;
            const float f0 = exp2f(transitions[j * KK + i0 + 0] * L2E);
            const float f1 = exp2f(transitions[j * KK + i0 + 1] * L2E);
            const float f2 = exp2f(transitions[j * KK + i0 + 2] * L2E);
            const float f3 = exp2f(transitions[j * KK + i0 + 3] * L2E);
            A[mt][kt] = mk4(pk_bf16(f0, f1), pk_bf16(f2, f3));
        }
    }

    // ---- B init: u0[i][n] = 2^((start[i]+em[bn][0][i])*L2E - C0_n) ----
    const float C0 = (start_t[0] + emn[0]) * L2E;   // anchor: state 0 of this column
    short4v Bf[3];
    #pragma unroll
    for (int kt = 0; kt < 3; ++kt) {
        const int i0 = 16 * kt + 4 * g;
        const float4 e0 = *(const float4*)(emn + i0);
        const float u0 = exp2f((start_t[i0 + 0] + e0.x) * L2E - C0);
        const float u1 = exp2f((start_t[i0 + 1] + e0.y) * L2E - C0);
        const float u2 = exp2f((start_t[i0 + 2] + e0.z) * L2E - C0);
        const float u3 = exp2f((start_t[i0 + 3] + e0.w) * L2E - C0);
        Bf[kt] = mk4(pk_bf16(u0, u1), pk_bf16(u2, u3));
    }
    float CS  = C0;     // log2-domain running offset (per column, 4 redundant lanes)
    float lrz = 0.0f;   // log2 of pending reciprocal normalizer
    const int baddr = n * 4;   // bpermute byte address: pull from lane n (g==0)

    auto step = [&](int t, const float4& c0, const float4& c1, const float4& c2) {
        // w = exp2(em*L2E + lrz)  — rz folded into the exponent
        float w[12];
        w[0] = exp2f(fmaf(c0.x, L2E, lrz)); w[1] = exp2f(fmaf(c0.y, L2E, lrz));
        w[2] = exp2f(fmaf(c0.z, L2E, lrz)); w[3] = exp2f(fmaf(c0.w, L2E, lrz));
        w[4] = exp2f(fmaf(c1.x, L2E, lrz)); w[5] = exp2f(fmaf(c1.y, L2E, lrz));
        w[6] = exp2f(fmaf(c1.z, L2E, lrz)); w[7] = exp2f(fmaf(c1.w, L2E, lrz));
        w[8] = exp2f(fmaf(c2.x, L2E, lrz)); w[9] = exp2f(fmaf(c2.y, L2E, lrz));
        w[10] = exp2f(fmaf(c2.z, L2E, lrz)); w[11] = exp2f(fmaf(c2.w, L2E, lrz));

        floatx4 a0 = {0.f, 0.f, 0.f, 0.f}, a1 = a0, a2 = a0;
        a0 = mfma16(A[0][0], Bf[0], a0); a0 = mfma16(A[0][1], Bf[1], a0);
        a0 = mfma16(A[0][2], Bf[2], a0);
        a1 = mfma16(A[1][0], Bf[0], a1); a1 = mfma16(A[1][1], Bf[1], a1);
        a1 = mfma16(A[1][2], Bf[2], a1);
        a2 = mfma16(A[2][0], Bf[0], a2); a2 = mfma16(A[2][1], Bf[1], a2);
        a2 = mfma16(A[2][2], Bf[2], a2);

        float un[12];
        un[0] = a0[0] * w[0]; un[1] = a0[1] * w[1]; un[2] = a0[2] * w[2]; un[3] = a0[3] * w[3];
        un[4] = a1[0] * w[4]; un[5] = a1[1] * w[5]; un[6] = a1[2] * w[6]; un[7] = a1[3] * w[7];
        un[8] = a2[0] * w[8]; un[9] = a2[1] * w[9]; un[10] = a2[2] * w[10]; un[11] = a2[3] * w[11];

        // z_n = new row-0 value of column n (lives on lane n, g==0, reg 0)
        const float z = __int_as_float(
            __builtin_amdgcn_ds_bpermute(baddr, __float_as_int(un[0])));
        const bool act = (t < Lc);

        #pragma unroll
        for (int mt = 0; mt < 3; ++mt) {
            const unsigned lo = pk_bf16(un[4 * mt + 0], un[4 * mt + 1]);
            const unsigned hi = pk_bf16(un[4 * mt + 2], un[4 * mt + 3]);
            Bf[mt] = mk4(act ? lo : gu(Bf[mt], 0), act ? hi : gu(Bf[mt], 1));
        }
        const float lz = log2f(z);
        CS  = act ? (CS + lz) : CS;
        lrz = act ? (-lz) : lrz;
    };

    // ---- main loop with PF-deep register prefetch ring ----
    float4 R[PF][3];
    #pragma unroll
    for (int k = 0; k < PF; ++k) {
        int tt = 1 + k; tt = (tt < TT) ? tt : (TT - 1);
        const float* p = emn + (size_t)tt * KK + 4 * g;
        R[k][0] = *(const float4*)(p);
        R[k][1] = *(const float4*)(p + 16);
        R[k][2] = *(const float4*)(p + 32);
    }
    int t = 1;
    for (; t + PF <= Lmax; t += PF) {
        #pragma unroll
        for (int k = 0; k < PF; ++k) {
            const float4 c0 = R[k][0], c1 = R[k][1], c2 = R[k][2];
            int tp = t + k + PF; tp = (tp < TT) ? tp : (TT - 1);
            const float* p = emn + (size_t)tp * KK + 4 * g;
            R[k][0] = *(const float4*)(p);
            R[k][1] = *(const float4*)(p + 16);
            R[k][2] = *(const float4*)(p + 32);
            step(t + k, c0, c1, c2);
        }
    }
    #pragma unroll
    for (int k = 0; k < PF; ++k)
        if (t + k < Lmax) step(t + k, R[k][0], R[k][1], R[k][2]);

    // ---- finalize: den_n = ln2 * (CS + log2( sum_j u[j]*rz*exp(end[j]) )) ----
    const float rz = exp2f(lrz);
    float psum = 0.0f;
    #pragma unroll
    for (int mt = 0; mt < 3; ++mt) {
        const int j0 = 16 * mt + 4 * g;
        const unsigned lo = gu(Bf[mt], 0), hi = gu(Bf[mt], 1);
        const float u0 = __uint_as_float(lo << 16);
        const float u1 = __uint_as_float(lo & 0xffff0000u);
        const float u2 = __uint_as_float(hi << 16);
        const float u3 = __uint_as_float(hi & 0xffff0000u);
        psum += u0 * exp2f(end_t[j0 + 0] * L2E);
        psum += u1 * exp2f(end_t[j0 + 1] * L2E);
        psum += u2 * exp2f(end_t[j0 + 2] * L2E);
        psum += u3 * exp2f(end_t[j0 + 3] * L2E);
    }
    psum *= rz;
    psum += __shfl_xor(psum, 16, 64);
    psum += __shfl_xor(psum, 32, 64);
    const float den = LN2 * (CS + log2f(psum));
    if (lane < 16) ws_d[base + lane] = den;
}

__global__ __launch_bounds__(256) void crf_combine(
    const float* __restrict__ ws_s, const float* __restrict__ ws_d,
    float* __restrict__ out)
{
    const int i = blockIdx.x * 256 + threadIdx.x;
    if (i < BB) out[i] = ws_s[i] - ws_d[i];
}

extern "C" void kernel_launch(void* const* d_in, const int* in_sizes, int n_in,
                              void* d_out, int out_size, void* d_ws, size_t ws_size,
                              hipStream_t stream) {
    const float* emissions   = (const float*)d_in[0];
    const int*   tags        = (const int*)  d_in[1];
    const void*  mask        = (const void*) d_in[2];
    const float* transitions = (const float*)d_in[3];
    const float* start_t     = (const float*)d_in[4];
    const float* end_t       = (const float*)d_in[5];
    float* out  = (float*)d_out;
    float* ws_s = (float*)d_ws;          // 512 floats
    float* ws_d = ws_s + BB;             // 512 floats

    crf_fused<<<BB + BB / 16, 64, 0, stream>>>(emissions, tags, mask, transitions,
                                               start_t, end_t, ws_s, ws_d);
    crf_combine<<<2, 256, 0, stream>>>(ws_s, ws_d, out);
}

// Round 6
// 331.733 us; speedup vs baseline: 1.5737x; 1.5737x over previous
//
#include <hip/hip_runtime.h>
#include <math.h>

#define BB 512
#define TT 1024
#define KK 48
#define PF 6   // emission prefetch depth (register ring)

static constexpr float L2E = 1.4426950408889634f;   // log2(e)
static constexpr float LN2 = 0.6931471805599453f;   // ln(2)

__device__ __forceinline__ float wave_reduce_sum_f(float v) {
    #pragma unroll
    for (int m = 32; m >= 1; m >>= 1) v += __shfl_xor(v, m, 64);
    return v;
}
__device__ __forceinline__ int wave_reduce_sum_i(int v) {
    #pragma unroll
    for (int m = 32; m >= 1; m >>= 1) v += __shfl_xor(v, m, 64);
    return v;
}

// wave-uniform broadcast of lane i's value — v_readlane (VALU->SGPR), the
// SGPR result feeds v_fma's single-SGPR operand slot directly.
__device__ __forceinline__ float rlane(float v, int i) {
    return __uint_as_float(__builtin_amdgcn_readlane(__float_as_uint(v), i));
}

// Fused: blocks [0,512) = numerator (one wave per batch),
//        blocks [512,1024) = denominator (one wave per batch, vector matvec).
// launch_bounds(64, 1): only 1 wave/EU required -> full VGPR budget, so the
// 48-entry M row stays register-resident (round-4 showed VGPR=52 => spilled).
__global__ __launch_bounds__(64, 1) void crf_fused(
    const float* __restrict__ emissions,   // (B, T, K)
    const int*   __restrict__ tags,        // (B, T)
    const void*  __restrict__ mask,        // (B, T) — dtype probed
    const float* __restrict__ transitions, // (K, K)
    const float* __restrict__ start_t,     // (K,)
    const float* __restrict__ end_t,       // (K,)
    float*       __restrict__ ws_s,        // (B,) path scores
    float*       __restrict__ ws_d)        // (B,) log-denominators
{
    const int lane = threadIdx.x;
    const unsigned w0 = *((const unsigned*)mask);

    if (blockIdx.x < BB) {
        // ===== numerator (verbatim from passing rounds) =====
        const int b = blockIdx.x;
        const float* em = emissions + (size_t)b * TT * KK;
        const int*   tg = tags      + (size_t)b * TT;
        int c = 0;
        if (w0 == 1u) {
            const int* mp = (const int*)mask + (size_t)b * TT;
            for (int t = lane; t < TT; t += 64) c += (mp[t] != 0);
        } else if (w0 == 0x3f800000u) {
            const float* mp = (const float*)mask + (size_t)b * TT;
            for (int t = lane; t < TT; t += 64) c += (mp[t] != 0.0f);
        } else {
            const unsigned char* mp = (const unsigned char*)mask + (size_t)b * TT;
            for (int t = lane; t < TT; t += 64) c += (mp[t] != 0);
        }
        const int L = wave_reduce_sum_i(c);
        float sc = 0.0f;
        for (int t = lane; t < TT; t += 64) {
            if (t < L) {
                const int tagt = tg[t];
                float term = em[(size_t)t * KK + tagt];
                term += (t == 0) ? start_t[tagt] : transitions[tg[t - 1] * KK + tagt];
                sc += term;
            }
        }
        sc = wave_reduce_sum_f(sc);
        if (lane == 0) ws_s[b] = sc + end_t[tg[L - 1]];
        return;
    }

    // ===== denominator: scaled linear-space forward, one wave per batch =====
    const int b = blockIdx.x - BB;
    const float* em = emissions + (size_t)b * TT * KK;

    int c = 0;
    if (w0 == 1u) {
        const int* mp = (const int*)mask + (size_t)b * TT;
        for (int t = lane; t < TT; t += 64) c += (mp[t] != 0);
    } else if (w0 == 0x3f800000u) {
        const float* mp = (const float*)mask + (size_t)b * TT;
        for (int t = lane; t < TT; t += 64) c += (mp[t] != 0.0f);
    } else {
        const unsigned char* mp = (const unsigned char*)mask + (size_t)b * TT;
        for (int t = lane; t < TT; t += 64) c += (mp[t] != 0);
    }
    const int L = wave_reduce_sum_i(c);

    const int j  = lane;
    const int jj = (j < KK) ? j : 0;
    // M[j][i] = exp(transitions[j][i]) — row per lane, 48 VGPRs, loop-invariant
    float M[KK];
    #pragma unroll
    for (int i = 0; i < KK; ++i) M[i] = exp2f(transitions[jj * KK + i] * L2E);

    const float A0 = (start_t[jj] + em[jj]) * L2E;
    const float C0 = rlane(A0, 0);
    float u   = exp2f(A0 - C0);   // lanes >= 48: garbage, never broadcast
    float lrz = 0.0f;             // -log2(z_prev), folded into emission exponent
    float CS  = C0;               // log2-domain running offset

    float cur[PF];
    #pragma unroll
    for (int k = 0; k < PF; ++k) {
        const int tt = (1 + k < TT) ? (1 + k) : (TT - 1);
        cur[k] = em[(size_t)tt * KK + jj];
    }

    int t = 1;
    for (; t + PF <= L; t += PF) {
        float nxt[PF];
        #pragma unroll
        for (int k = 0; k < PF; ++k) {
            int tt = t + PF + k;
            tt = (tt < TT) ? tt : (TT - 1);
            nxt[k] = em[(size_t)tt * KK + jj];
        }
        #pragma unroll
        for (int k = 0; k < PF; ++k) {
            // E = exp2(em*L2E + lrz): normalizer folded in; both transcendentals
            // (this exp2 and prev step's log2) run in the FMA phase's slack.
            const float E = exp2f(fmaf(cur[k], L2E, lrz));
            float a0=0.f,a1=0.f,a2=0.f,a3=0.f,a4=0.f,a5=0.f,a6=0.f,a7=0.f;
            #pragma unroll
            for (int r = 0; r < 6; ++r) {          // 48 readlane + 48 FMA
                a0 = fmaf(M[8*r+0], rlane(u, 8*r+0), a0);
                a1 = fmaf(M[8*r+1], rlane(u, 8*r+1), a1);
                a2 = fmaf(M[8*r+2], rlane(u, 8*r+2), a2);
                a3 = fmaf(M[8*r+3], rlane(u, 8*r+3), a3);
                a4 = fmaf(M[8*r+4], rlane(u, 8*r+4), a4);
                a5 = fmaf(M[8*r+5], rlane(u, 8*r+5), a5);
                a6 = fmaf(M[8*r+6], rlane(u, 8*r+6), a6);
                a7 = fmaf(M[8*r+7], rlane(u, 8*r+7), a7);
            }
            const float s = (((a0+a1)+(a2+a3)) + ((a4+a5)+(a6+a7)));
            u = s * E;
            const float z  = rlane(u, 0);          // consumed next step (slack)
            const float lz = log2f(z);
            CS  += lz;
            lrz  = -lz;
        }
        #pragma unroll
        for (int k = 0; k < PF; ++k) cur[k] = nxt[k];
    }
    #pragma unroll
    for (int k = 0; k < PF; ++k) {
        if (t + k < L) {
            const float E = exp2f(fmaf(cur[k], L2E, lrz));
            float a0=0.f,a1=0.f,a2=0.f,a3=0.f,a4=0.f,a5=0.f,a6=0.f,a7=0.f;
            #pragma unroll
            for (int r = 0; r < 6; ++r) {
                a0 = fmaf(M[8*r+0], rlane(u, 8*r+0), a0);
                a1 = fmaf(M[8*r+1], rlane(u, 8*r+1), a1);
                a2 = fmaf(M[8*r+2], rlane(u, 8*r+2), a2);
                a3 = fmaf(M[8*r+3], rlane(u, 8*r+3), a3);
                a4 = fmaf(M[8*r+4], rlane(u, 8*r+4), a4);
                a5 = fmaf(M[8*r+5], rlane(u, 8*r+5), a5);
                a6 = fmaf(M[8*r+6], rlane(u, 8*r+6), a6);
                a7 = fmaf(M[8*r+7], rlane(u, 8*r+7), a7);
            }
            const float s = (((a0+a1)+(a2+a3)) + ((a4+a5)+(a6+a7)));
            u = s * E;
            const float z  = rlane(u, 0);
            const float lz = log2f(z);
            CS  += lz;
            lrz  = -lz;
        }
    }

    // log_den = ln2 * (CS + log2(sum_j u[j] * 2^(end[j]*L2E + lrz)))
    const float contrib = (j < KK) ? u * exp2f(fmaf(end_t[jj], L2E, lrz)) : 0.0f;
    const float ssum    = wave_reduce_sum_f(contrib);
    if (lane == 0) ws_d[b] = LN2 * (CS + log2f(ssum));
}

__global__ __launch_bounds__(256) void crf_combine(
    const float* __restrict__ ws_s, const float* __restrict__ ws_d,
    float* __restrict__ out)
{
    const int i = blockIdx.x * 256 + threadIdx.x;
    if (i < BB) out[i] = ws_s[i] - ws_d[i];
}

extern "C" void kernel_launch(void* const* d_in, const int* in_sizes, int n_in,
                              void* d_out, int out_size, void* d_ws, size_t ws_size,
                              hipStream_t stream) {
    const float* emissions   = (const float*)d_in[0];
    const int*   tags        = (const int*)  d_in[1];
    const void*  mask        = (const void*) d_in[2];
    const float* transitions = (const float*)d_in[3];
    const float* start_t     = (const float*)d_in[4];
    const float* end_t       = (const float*)d_in[5];
    float* out  = (float*)d_out;
    float* ws_s = (float*)d_ws;          // 512 floats
    float* ws_d = ws_s + BB;             // 512 floats

    crf_fused<<<2 * BB, 64, 0, stream>>>(emissions, tags, mask, transitions,
                                         start_t, end_t, ws_s, ws_d);
    crf_combine<<<2, 256, 0, stream>>>(ws_s, ws_d, out);
}

// Round 7
// 330.833 us; speedup vs baseline: 1.5780x; 1.0027x over previous
//
#include <hip/hip_runtime.h>
#include <math.h>

#define BB 512
#define TT 1024
#define KK 48
#define PF 6   // emission prefetch depth (register ring)

static constexpr float L2E = 1.4426950408889634f;   // log2(e)
static constexpr float LN2 = 0.6931471805599453f;   // ln(2)

__device__ __forceinline__ float wave_reduce_sum_f(float v) {
    #pragma unroll
    for (int m = 32; m >= 1; m >>= 1) v += __shfl_xor(v, m, 64);
    return v;
}
__device__ __forceinline__ int wave_reduce_sum_i(int v) {
    #pragma unroll
    for (int m = 32; m >= 1; m >>= 1) v += __shfl_xor(v, m, 64);
    return v;
}

// wave-uniform broadcast of lane i's value via v_readlane (result in SGPR).
__device__ __forceinline__ float rlane(float v, int i) {
    return __uint_as_float(__builtin_amdgcn_readlane(__float_as_uint(v), i));
}

// Matvec core: s = M . u (u broadcast from lanes). Readlanes batched in
// phases of 16 so every SGPR write has >=15 instructions before its reader —
// hides the ~5-state VALU-write-SGPR -> VALU-read-SGPR hazard that round 6's
// pairwise rlane->fma pattern paid per element (~300 cy/step of s_nops).
__device__ __forceinline__ float matvec48(const float* __restrict__ M, float u) {
    float a[8];
    #pragma unroll
    for (int i = 0; i < 8; ++i) a[i] = 0.0f;
    #pragma unroll
    for (int p = 0; p < 3; ++p) {
        float x[16];
        #pragma unroll
        for (int i = 0; i < 16; ++i) x[i] = rlane(u, 16 * p + i);
        #pragma unroll
        for (int i = 0; i < 16; ++i)
            a[i & 7] = fmaf(M[16 * p + i], x[i], a[i & 7]);
    }
    return (((a[0] + a[1]) + (a[2] + a[3])) + ((a[4] + a[5]) + (a[6] + a[7])));
}

// Fused: blocks [0,512) = numerator (one wave per batch),
//        blocks [512,1024) = denominator (one wave per batch, vector matvec).
__global__ __launch_bounds__(64, 1) void crf_fused(
    const float* __restrict__ emissions,   // (B, T, K)
    const int*   __restrict__ tags,        // (B, T)
    const void*  __restrict__ mask,        // (B, T) — dtype probed
    const float* __restrict__ transitions, // (K, K)
    const float* __restrict__ start_t,     // (K,)
    const float* __restrict__ end_t,       // (K,)
    float*       __restrict__ ws_s,        // (B,) path scores
    float*       __restrict__ ws_d)        // (B,) log-denominators
{
    const int lane = threadIdx.x;
    const unsigned w0 = *((const unsigned*)mask);

    if (blockIdx.x < BB) {
        // ===== numerator (verbatim from passing rounds) =====
        const int b = blockIdx.x;
        const float* em = emissions + (size_t)b * TT * KK;
        const int*   tg = tags      + (size_t)b * TT;
        int c = 0;
        if (w0 == 1u) {
            const int* mp = (const int*)mask + (size_t)b * TT;
            for (int t = lane; t < TT; t += 64) c += (mp[t] != 0);
        } else if (w0 == 0x3f800000u) {
            const float* mp = (const float*)mask + (size_t)b * TT;
            for (int t = lane; t < TT; t += 64) c += (mp[t] != 0.0f);
        } else {
            const unsigned char* mp = (const unsigned char*)mask + (size_t)b * TT;
            for (int t = lane; t < TT; t += 64) c += (mp[t] != 0);
        }
        const int L = wave_reduce_sum_i(c);
        float sc = 0.0f;
        for (int t = lane; t < TT; t += 64) {
            if (t < L) {
                const int tagt = tg[t];
                float term = em[(size_t)t * KK + tagt];
                term += (t == 0) ? start_t[tagt] : transitions[tg[t - 1] * KK + tagt];
                sc += term;
            }
        }
        sc = wave_reduce_sum_f(sc);
        if (lane == 0) ws_s[b] = sc + end_t[tg[L - 1]];
        return;
    }

    // ===== denominator: scaled linear-space forward, one wave per batch =====
    const int b = blockIdx.x - BB;
    const float* em = emissions + (size_t)b * TT * KK;

    int c = 0;
    if (w0 == 1u) {
        const int* mp = (const int*)mask + (size_t)b * TT;
        for (int t = lane; t < TT; t += 64) c += (mp[t] != 0);
    } else if (w0 == 0x3f800000u) {
        const float* mp = (const float*)mask + (size_t)b * TT;
        for (int t = lane; t < TT; t += 64) c += (mp[t] != 0.0f);
    } else {
        const unsigned char* mp = (const unsigned char*)mask + (size_t)b * TT;
        for (int t = lane; t < TT; t += 64) c += (mp[t] != 0);
    }
    const int L = wave_reduce_sum_i(c);

    const int j  = lane;
    const int jj = (j < KK) ? j : 0;
    // M[j][i] = exp(transitions[j][i]) — row per lane, loop-invariant
    float M[KK];
    #pragma unroll
    for (int i = 0; i < KK; ++i) M[i] = exp2f(transitions[jj * KK + i] * L2E);

    const float A0 = (start_t[jj] + em[jj]) * L2E;
    const float C0 = rlane(A0, 0);
    float u   = exp2f(A0 - C0);   // lanes >= 48: garbage, never broadcast
    float lrz = 0.0f;             // -log2(z_prev), folded into emission exponent
    float CS  = C0;               // log2-domain running offset

    float cur[PF];
    #pragma unroll
    for (int k = 0; k < PF; ++k) {
        const int tt = (1 + k < TT) ? (1 + k) : (TT - 1);
        cur[k] = em[(size_t)tt * KK + jj];
    }

    int t = 1;
    for (; t + PF <= L; t += PF) {
        float nxt[PF];
        #pragma unroll
        for (int k = 0; k < PF; ++k) {
            int tt = t + PF + k;
            tt = (tt < TT) ? tt : (TT - 1);
            nxt[k] = em[(size_t)tt * KK + jj];
        }
        #pragma unroll
        for (int k = 0; k < PF; ++k) {
            const float E = exp2f(fmaf(cur[k], L2E, lrz));   // normalizer folded
            const float s = matvec48(M, u);
            u = s * E;
            const float z  = rlane(u, 0);       // consumed next step (slack)
            const float lz = log2f(z);
            CS  += lz;
            lrz  = -lz;
        }
        #pragma unroll
        for (int k = 0; k < PF; ++k) cur[k] = nxt[k];
    }
    #pragma unroll
    for (int k = 0; k < PF; ++k) {
        if (t + k < L) {
            const float E = exp2f(fmaf(cur[k], L2E, lrz));
            const float s = matvec48(M, u);
            u = s * E;
            const float z  = rlane(u, 0);
            const float lz = log2f(z);
            CS  += lz;
            lrz  = -lz;
        }
    }

    // log_den = ln2 * (CS + log2(sum_j u[j] * 2^(end[j]*L2E + lrz)))
    const float contrib = (j < KK) ? u * exp2f(fmaf(end_t[jj], L2E, lrz)) : 0.0f;
    const float ssum    = wave_reduce_sum_f(contrib);
    if (lane == 0) ws_d[b] = LN2 * (CS + log2f(ssum));
}

__global__ __launch_bounds__(256) void crf_combine(
    const float* __restrict__ ws_s, const float* __restrict__ ws_d,
    float* __restrict__ out)
{
    const int i = blockIdx.x * 256 + threadIdx.x;
    if (i < BB) out[i] = ws_s[i] - ws_d[i];
}

extern "C" void kernel_launch(void* const* d_in, const int* in_sizes, int n_in,
                              void* d_out, int out_size, void* d_ws, size_t ws_size,
                              hipStream_t stream) {
    const float* emissions   = (const float*)d_in[0];
    const int*   tags        = (const int*)  d_in[1];
    const void*  mask        = (const void*) d_in[2];
    const float* transitions = (const float*)d_in[3];
    const float* start_t     = (const float*)d_in[4];
    const float* end_t       = (const float*)d_in[5];
    float* out  = (float*)d_out;
    float* ws_s = (float*)d_ws;          // 512 floats
    float* ws_d = ws_s + BB;             // 512 floats

    crf_fused<<<2 * BB, 64, 0, stream>>>(emissions, tags, mask, transitions,
                                         start_t, end_t, ws_s, ws_d);
    crf_combine<<<2, 256, 0, stream>>>(ws_s, ws_d, out);
}

// Round 9
// 296.207 us; speedup vs baseline: 1.7624x; 1.1169x over previous
//
#include <hip/hip_runtime.h>
#include <math.h>

#define BB 512
#define TT 1024
#define KK 48
#define PF 6   // emission prefetch depth (register ring)

typedef _Float16 half2v __attribute__((ext_vector_type(2)));

static constexpr float L2E = 1.4426950408889634f;   // log2(e)
static constexpr float LN2 = 0.6931471805599453f;   // ln(2)
static constexpr float SC  = 12.0f;  // state kept at 2^-12 scale for f16 range

__device__ __forceinline__ float wave_reduce_sum_f(float v) {
    #pragma unroll
    for (int m = 32; m >= 1; m >>= 1) v += __shfl_xor(v, m, 64);
    return v;
}
__device__ __forceinline__ int wave_reduce_sum_i(int v) {
    #pragma unroll
    for (int m = 32; m >= 1; m >>= 1) v += __shfl_xor(v, m, 64);
    return v;
}

__device__ __forceinline__ float rlane(float v, int i) {
    return __uint_as_float(__builtin_amdgcn_readlane(__float_as_uint(v), i));
}

// f16x2 dot product with f32 accumulate: v_dot2_f32_f16 (2 MACs / instr)
__device__ __forceinline__ float dot2(unsigned a, unsigned b, float c) {
#if __has_builtin(__builtin_amdgcn_fdot2)
    union { unsigned u; half2v h; } ua, ub;
    ua.u = a; ub.u = b;
    return __builtin_amdgcn_fdot2(ua.h, ub.h, c, false);
#else
    union { unsigned u; half2v h; } ua, ub;
    ua.u = a; ub.u = b;
    return c + (float)ua.h.x * (float)ub.h.x + (float)ua.h.y * (float)ub.h.y;
#endif
}

// Pack (u[j], u[j+1]) as f16x2 entirely in-register:
// cvt_f16 -> DPP quad_perm [1,0,3,2] (swap neighbor, VALU) -> byte-perm.
// Even lane j ends with (lo = u[j], hi = u[j+1]); readlanes target even lanes.
__device__ __forceinline__ unsigned pack_pair(float u) {
    union { _Float16 h; unsigned short s; } cv;
    cv.h = (_Float16)u;
    const unsigned own = cv.s;
    const unsigned nbr = (unsigned)__builtin_amdgcn_update_dpp(
        (int)own, (int)own, 0xB1 /*quad_perm [1,0,3,2]*/, 0xF, 0xF, false);
    return __builtin_amdgcn_perm(nbr, own, 0x05040100);  // own lo16 | nbr lo16 << 16
}

// Fused: blocks [0,512) = numerator, blocks [512,1024) = denominator.
__global__ __launch_bounds__(64, 1) void crf_fused(
    const float* __restrict__ emissions,   // (B, T, K)
    const int*   __restrict__ tags,        // (B, T)
    const void*  __restrict__ mask,        // (B, T) — dtype probed
    const float* __restrict__ transitions, // (K, K)
    const float* __restrict__ start_t,     // (K,)
    const float* __restrict__ end_t,       // (K,)
    float*       __restrict__ ws_s,        // (B,) path scores
    float*       __restrict__ ws_d)        // (B,) log-denominators
{
    const int lane = threadIdx.x;
    const unsigned w0 = *((const unsigned*)mask);

    if (blockIdx.x < BB) {
        // ===== numerator (verbatim from passing rounds) =====
        const int b = blockIdx.x;
        const float* em = emissions + (size_t)b * TT * KK;
        const int*   tg = tags      + (size_t)b * TT;
        int c = 0;
        if (w0 == 1u) {
            const int* mp = (const int*)mask + (size_t)b * TT;
            for (int t = lane; t < TT; t += 64) c += (mp[t] != 0);
        } else if (w0 == 0x3f800000u) {
            const float* mp = (const float*)mask + (size_t)b * TT;
            for (int t = lane; t < TT; t += 64) c += (mp[t] != 0.0f);
        } else {
            const unsigned char* mp = (const unsigned char*)mask + (size_t)b * TT;
            for (int t = lane; t < TT; t += 64) c += (mp[t] != 0);
        }
        const int L = wave_reduce_sum_i(c);
        float sc = 0.0f;
        for (int t = lane; t < TT; t += 64) {
            if (t < L) {
                const int tagt = tg[t];
                float term = em[(size_t)t * KK + tagt];
                term += (t == 0) ? start_t[tagt] : transitions[tg[t - 1] * KK + tagt];
                sc += term;
            }
        }
        sc = wave_reduce_sum_f(sc);
        if (lane == 0) ws_s[b] = sc + end_t[tg[L - 1]];
        return;
    }

    // ===== denominator: scaled linear-space forward, f16x2 dot2 =====
    const int b = blockIdx.x - BB;
    const float* em = emissions + (size_t)b * TT * KK;

    int c = 0;
    if (w0 == 1u) {
        const int* mp = (const int*)mask + (size_t)b * TT;
        for (int t = lane; t < TT; t += 64) c += (mp[t] != 0);
    } else if (w0 == 0x3f800000u) {
        const float* mp = (const float*)mask + (size_t)b * TT;
        for (int t = lane; t < TT; t += 64) c += (mp[t] != 0.0f);
    } else {
        const unsigned char* mp = (const unsigned char*)mask + (size_t)b * TT;
        for (int t = lane; t < TT; t += 64) c += (mp[t] != 0);
    }
    const int L = wave_reduce_sum_i(c);

    const int j  = lane;
    const int jj = (j < KK) ? j : 0;
    // M row packed as 24 f16x2: Mp[i] = (M[j][2i], M[j][2i+1]), M = exp(T)
    unsigned Mp[KK / 2];
    #pragma unroll
    for (int i = 0; i < KK / 2; ++i) {
        union { _Float16 h; unsigned short s; } h0, h1;
        h0.h = (_Float16)exp2f(transitions[jj * KK + 2 * i]     * L2E);
        h1.h = (_Float16)exp2f(transitions[jj * KK + 2 * i + 1] * L2E);
        Mp[i] = (unsigned)h0.s | ((unsigned)h1.s << 16);
    }

    // init at 2^-SC scale: u'_0 = 2^(A0 - C0 - SC); invariant CS - lz = C0
    // with lz_0 = -SC  =>  CS_0 = C0 - SC, pending lrz_0 = -lz_0 - SC = 0.
    const float A0 = (start_t[jj] + em[jj]) * L2E;
    const float C0 = rlane(A0, 0);
    float u   = exp2f(A0 - C0 - SC);
    float lrz = 0.0f;
    float CS  = C0 - SC;
    unsigned upk = pack_pair(u);  // packed state pairs (valid on even lanes)

    float cur[PF];
    #pragma unroll
    for (int k = 0; k < PF; ++k) {
        const int tt = (1 + k < TT) ? (1 + k) : (TT - 1);
        cur[k] = em[(size_t)tt * KK + jj];
    }

    int t = 1;
    for (; t + PF <= L; t += PF) {
        float nxt[PF];
        #pragma unroll
        for (int k = 0; k < PF; ++k) {
            int tt = t + PF + k;
            tt = (tt < TT) ? tt : (TT - 1);
            nxt[k] = em[(size_t)tt * KK + jj];
        }
        #pragma unroll
        for (int k = 0; k < PF; ++k) {
            const float E = exp2f(fmaf(cur[k], L2E, lrz));   // normalizer+scale folded
            unsigned x[KK / 2];
            #pragma unroll
            for (int i = 0; i < KK / 2; ++i)
                x[i] = (unsigned)__builtin_amdgcn_readlane((int)upk, 2 * i);
            float a0 = 0.f, a1 = 0.f, a2 = 0.f, a3 = 0.f;
            #pragma unroll
            for (int i = 0; i < KK / 2; i += 4) {
                a0 = dot2(x[i + 0], Mp[i + 0], a0);
                a1 = dot2(x[i + 1], Mp[i + 1], a1);
                a2 = dot2(x[i + 2], Mp[i + 2], a2);
                a3 = dot2(x[i + 3], Mp[i + 3], a3);
            }
            u = ((a0 + a1) + (a2 + a3)) * E;
            upk = pack_pair(u);                 // chain: cvt + dpp + perm
            const float z  = rlane(u, 0);       // off-chain (next-step slack)
            const float lz = log2f(z);
            CS  += lz + SC;
            lrz  = -lz - SC;
        }
        #pragma unroll
        for (int k = 0; k < PF; ++k) cur[k] = nxt[k];
    }
    #pragma unroll
    for (int k = 0; k < PF; ++k) {
        if (t + k < L) {
            const float E = exp2f(fmaf(cur[k], L2E, lrz));
            unsigned x[KK / 2];
            #pragma unroll
            for (int i = 0; i < KK / 2; ++i)
                x[i] = (unsigned)__builtin_amdgcn_readlane((int)upk, 2 * i);
            float a0 = 0.f, a1 = 0.f, a2 = 0.f, a3 = 0.f;
            #pragma unroll
            for (int i = 0; i < KK / 2; i += 4) {
                a0 = dot2(x[i + 0], Mp[i + 0], a0);
                a1 = dot2(x[i + 1], Mp[i + 1], a1);
                a2 = dot2(x[i + 2], Mp[i + 2], a2);
                a3 = dot2(x[i + 3], Mp[i + 3], a3);
            }
            u = ((a0 + a1) + (a2 + a3)) * E;
            upk = pack_pair(u);
            const float z  = rlane(u, 0);
            const float lz = log2f(z);
            CS  += lz + SC;
            lrz  = -lz - SC;
        }
    }

    // log_den = ln2 * (CS + SC + log2(sum_j u[j] * 2^(end[j]*L2E + lrz)))
    const float contrib = (j < KK) ? u * exp2f(fmaf(end_t[jj], L2E, lrz)) : 0.0f;
    const float ssum    = wave_reduce_sum_f(contrib);
    if (lane == 0) ws_d[b] = LN2 * (CS + SC + log2f(ssum));
}

__global__ __launch_bounds__(256) void crf_combine(
    const float* __restrict__ ws_s, const float* __restrict__ ws_d,
    float* __restrict__ out)
{
    const int i = blockIdx.x * 256 + threadIdx.x;
    if (i < BB) out[i] = ws_s[i] - ws_d[i];
}

extern "C" void kernel_launch(void* const* d_in, const int* in_sizes, int n_in,
                              void* d_out, int out_size, void* d_ws, size_t ws_size,
                              hipStream_t stream) {
    const float* emissions   = (const float*)d_in[0];
    const int*   tags        = (const int*)  d_in[1];
    const void*  mask        = (const void*) d_in[2];
    const float* transitions = (const float*)d_in[3];
    const float* start_t     = (const float*)d_in[4];
    const float* end_t       = (const float*)d_in[5];
    float* out  = (float*)d_out;
    float* ws_s = (float*)d_ws;          // 512 floats
    float* ws_d = ws_s + BB;             // 512 floats

    crf_fused<<<2 * BB, 64, 0, stream>>>(emissions, tags, mask, transitions,
                                         start_t, end_t, ws_s, ws_d);
    crf_combine<<<2, 256, 0, stream>>>(ws_s, ws_d, out);
}